// Round 6
// baseline (559.080 us; speedup 1.0000x reference)
//
#include <hip/hip_runtime.h>

// CrossAttention B=8, N=M=2048, D=HID=OUT=1024. fp32 in / fp32 out, int32 mask.
//
// Round-10 RESUBMIT (round-5 bench was an infra failure: "container failed
// twice", no kernel verdict. Hang-risk audit: barriers are wave-uniform
// (EPI/GDEC compile-time), vmcnt schedule never waits on more than issued,
// addressing in-bounds. Resubmitting unchanged for the measurement.)
//
// Mask prefetch with SLACK. R3 (16-tile window) beat R4 (32-tile) —
// per-in-window-tile cost is ~constant (stall/disruption), so: back to the
// 16-tile window, but give mask loads 1.5 tiles of issue->forced-wait budget:
//   - mask issued AFTER tile t's staging; window tiles end with vmcnt(12):
//     keeps {stg t+3 (4), mask u (8)} in flight, forces {stg t+2, mask u-1} —
//     staging discipline identical to vmcnt(4)'s (stg t+2 complete 1 barrier
//     before its reads), mask u forced only at end of tile u+17.
//   - pack mask u two tiles after issue (double mv buffers, STATIC parity
//     index via 2-unrolled window loop; runtime-indexed arrays -> scratch).
//   - tails (nt-3..nt-1): vmcnt(12), vmcnt(8), vmcnt(8)... vmcnt(0);
//     packs of u=14,15 post-loop. Queue audit in comments at each site.
// Epilogue unchanged: C = bit ? exp(acc/32) : 0  (== exp(-1e10/32)).
// EPI==1 requires nt==32 (K=1024) — true for the S GEMM call.
// QK fusion (GDEC=2) kept from round-9 (neutral). Everything else = round-7
// core: 256^2 tile, ring-4 counted-vmcnt, 1 barrier/tile, XOR swizzle
// (0 bank conflicts measured), fused rowsum out-GEMM.
//
// Buffers (peak ws = 100,663,296 B):
//   h1f ws@0           33.5 MB (dead after Q)    -> Vt reuses
//   h2f ws@33,554,432  33.5 MB (dead after Vt)
//   Wf  ws@67,108,864   6.3 MB (dead after Vt)
//   SP  ws@33,554,432  67.1 MB (over dead h2f+Wf)
//   Qf  d_out lo half, Kp d_out hi half (dead before final fp32 write)

using f16   = _Float16;
using f16x4 = __attribute__((ext_vector_type(4))) _Float16;
using f16x8 = __attribute__((ext_vector_type(8))) _Float16;
using f32x4 = __attribute__((ext_vector_type(4))) float;

typedef unsigned int u32_g __attribute__((address_space(1)));
typedef unsigned int u32_l __attribute__((address_space(3)));

__device__ __forceinline__ void gl_lds16(const f16* g, f16* l) {
    __builtin_amdgcn_global_load_lds((const u32_g*)g, (u32_l*)l, 16, 0, 0);
}

#define FENCE() asm volatile("" ::: "memory")
#define BAR()   do { FENCE(); __builtin_amdgcn_s_barrier(); FENCE(); } while (0)

// Mask prefetch (EPI==1). 8 dwords/tile, 16-tile window, idx = u*8+j.
// idx = rg*16 + cg*4 + r  (rg=idx>>4, cg=(idx>>2)&3, r=idx&3); bit pos = idx.
#define MASK_ISSUE_P(U_, MV_)                                            \
  { int idx0_ = (U_) * 8;                                                \
    _Pragma("unroll")                                                    \
    for (int j_ = 0; j_ < 8; ++j_) {                                     \
      int idx_ = idx0_ + j_;                                             \
      long off_ = (long)(((idx_ >> 4) * 16) + (idx_ & 3)) * N            \
                + (((idx_ >> 2) & 3) * 16);                              \
      MV_[j_] = Mrow[off_];                                              \
    } }

#define MASK_PACK_P(U_, MV_)                                             \
  { unsigned b_ = 0;                                                     \
    _Pragma("unroll")                                                    \
    for (int j_ = 0; j_ < 8; ++j_) b_ |= (MV_[j_] != 0 ? 1u : 0u) << j_; \
    unsigned sh_ = (unsigned)(((U_) & 3) * 8);                           \
    int w_ = (U_) >> 2;                                                  \
    mw[0] |= (w_ == 0) ? (b_ << sh_) : 0u;                               \
    mw[1] |= (w_ == 1) ? (b_ << sh_) : 0u;                               \
    mw[2] |= (w_ == 2) ? (b_ << sh_) : 0u;                               \
    mw[3] |= (w_ == 3) ? (b_ << sh_) : 0u;                               \
  }

// 16 MFMA: rows RG_..RG_+3 x all 4 col-groups (+4 rowsum MFMA for EPI 2).
#define MFMA_HALF(A0_, A1_, A2_, A3_, RG_)                                               \
  do {                                                                                   \
    if constexpr (EPI == 2) {                                                            \
      rs[RG_+0] = __builtin_amdgcn_mfma_f32_16x16x32_f16(A0_, bones, rs[RG_+0], 0,0,0);  \
      rs[RG_+1] = __builtin_amdgcn_mfma_f32_16x16x32_f16(A1_, bones, rs[RG_+1], 0,0,0);  \
      rs[RG_+2] = __builtin_amdgcn_mfma_f32_16x16x32_f16(A2_, bones, rs[RG_+2], 0,0,0);  \
      rs[RG_+3] = __builtin_amdgcn_mfma_f32_16x16x32_f16(A3_, bones, rs[RG_+3], 0,0,0);  \
    }                                                                                    \
    acc[RG_+0][0] = __builtin_amdgcn_mfma_f32_16x16x32_f16(A0_, b0, acc[RG_+0][0],0,0,0);\
    acc[RG_+0][1] = __builtin_amdgcn_mfma_f32_16x16x32_f16(A0_, b1, acc[RG_+0][1],0,0,0);\
    acc[RG_+0][2] = __builtin_amdgcn_mfma_f32_16x16x32_f16(A0_, b2, acc[RG_+0][2],0,0,0);\
    acc[RG_+0][3] = __builtin_amdgcn_mfma_f32_16x16x32_f16(A0_, b3, acc[RG_+0][3],0,0,0);\
    acc[RG_+1][0] = __builtin_amdgcn_mfma_f32_16x16x32_f16(A1_, b0, acc[RG_+1][0],0,0,0);\
    acc[RG_+1][1] = __builtin_amdgcn_mfma_f32_16x16x32_f16(A1_, b1, acc[RG_+1][1],0,0,0);\
    acc[RG_+1][2] = __builtin_amdgcn_mfma_f32_16x16x32_f16(A1_, b2, acc[RG_+1][2],0,0,0);\
    acc[RG_+1][3] = __builtin_amdgcn_mfma_f32_16x16x32_f16(A1_, b3, acc[RG_+1][3],0,0,0);\
    acc[RG_+2][0] = __builtin_amdgcn_mfma_f32_16x16x32_f16(A2_, b0, acc[RG_+2][0],0,0,0);\
    acc[RG_+2][1] = __builtin_amdgcn_mfma_f32_16x16x32_f16(A2_, b1, acc[RG_+2][1],0,0,0);\
    acc[RG_+2][2] = __builtin_amdgcn_mfma_f32_16x16x32_f16(A2_, b2, acc[RG_+2][2],0,0,0);\
    acc[RG_+2][3] = __builtin_amdgcn_mfma_f32_16x16x32_f16(A2_, b3, acc[RG_+2][3],0,0,0);\
    acc[RG_+3][0] = __builtin_amdgcn_mfma_f32_16x16x32_f16(A3_, b0, acc[RG_+3][0],0,0,0);\
    acc[RG_+3][1] = __builtin_amdgcn_mfma_f32_16x16x32_f16(A3_, b1, acc[RG_+3][1],0,0,0);\
    acc[RG_+3][2] = __builtin_amdgcn_mfma_f32_16x16x32_f16(A3_, b2, acc[RG_+3][2],0,0,0);\
    acc[RG_+3][3] = __builtin_amdgcn_mfma_f32_16x16x32_f16(A3_, b3, acc[RG_+3][3],0,0,0);\
  } while (0)

// Stage tile T_+3 into ring buffer (T_+3)&3 (4 gl_lds).
#define STAGE_T(T_)                                                      \
  { f16* dA_ = ldsAw + ((T_ + 3) & 3) * 16384;                           \
    f16* dB_ = ldsBw + ((T_ + 3) & 3) * 16384;                           \
    const f16* gA_ = gAs + (long)(T_ + 3) * 32;                          \
    const f16* gB_ = gBs + (long)(T_ + 3) * 32;                          \
    gl_lds16(gA_, dA_);                                                  \
    gl_lds16(gA_ + sweep, dA_ + 4096);                                   \
    gl_lds16(gB_, dB_);                                                  \
    gl_lds16(gB_ + sweep, dB_ + 4096); }

// ds_reads + 32 MFMA + counted vmcnt + barrier for tile T_.
#define COMPUTE_T(T_, VM_)                                               \
  { const f16* bufA_ = smem + ((T_) & 3) * 16384;                        \
    const f16* bufB_ = bufA_ + 8192;                                     \
    f16x8 a0_, a1_, a2_, a3_, a4_, a5_, a6_, a7_, b0, b1, b2, b3;        \
    a0_ = *(const f16x8*)(bufA_ + offA);                                 \
    a1_ = *(const f16x8*)(bufA_ + offA + 512);                           \
    a2_ = *(const f16x8*)(bufA_ + offA + 1024);                          \
    a3_ = *(const f16x8*)(bufA_ + offA + 1536);                          \
    b0  = *(const f16x8*)(bufB_ + offB);                                 \
    b1  = *(const f16x8*)(bufB_ + offB + 512);                           \
    b2  = *(const f16x8*)(bufB_ + offB + 1024);                          \
    b3  = *(const f16x8*)(bufB_ + offB + 1536);                          \
    a4_ = *(const f16x8*)(bufA_ + offA + 2048);                          \
    a5_ = *(const f16x8*)(bufA_ + offA + 2560);                          \
    a6_ = *(const f16x8*)(bufA_ + offA + 3072);                          \
    a7_ = *(const f16x8*)(bufA_ + offA + 3584);                          \
    __builtin_amdgcn_s_setprio(1);                                       \
    MFMA_HALF(a0_, a1_, a2_, a3_, 0);                                    \
    MFMA_HALF(a4_, a5_, a6_, a7_, 4);                                    \
    __builtin_amdgcn_s_setprio(0);                                       \
    asm volatile(VM_ ::: "memory");                                      \
    BAR(); }

#define VM12 "s_waitcnt vmcnt(12)"
#define VM8  "s_waitcnt vmcnt(8)"

// NT GEMM: C = A * B^T. A:(MxK) f16, B:(NxK) f16, row-major. 256x256 tile.
// EPI 0: f16 C.
// EPI 1: f16 C = bit ? exp(acc/32) : 0    [S GEMM, slack mask prefetch; nt==32]
// EPI 2: fp32 C = acc / rowsum(A)         [out GEMM, ones-MFMA sums]
// GDEC 0: 3D grid.
// GDEC 1: 1D grid, z=l&7, x=(l>>3)&(2^LGX-1), y=l>>(3+LGX).
// GDEC 2: fused QK pair: z=l>>8 (kind), x=l&3, y=(l>>2)&63; sA/sB/sC are the
//         element offsets between the two problems' buffers.
template <int EPI, int GDEC, int LGX>
__global__ __launch_bounds__(512, 2)
void gemm256_nt_f16(const f16* __restrict__ A, const f16* __restrict__ B,
                    void* __restrict__ Cv, const int* __restrict__ Mask,
                    int N, int K, long sA, long sB, long sC, long sMask)
{
    __shared__ f16 smem[4 * 16384];   // 4-deep ring: per buf A 8192 + B 8192 f16

    int bx, by, bz;
    if constexpr (GDEC == 0) {
        bx = blockIdx.x; by = blockIdx.y; bz = blockIdx.z;
    } else if constexpr (GDEC == 1) {
        int l = blockIdx.x;
        bz = l & 7; bx = (l >> 3) & ((1 << LGX) - 1); by = l >> (3 + LGX);
    } else {
        int l = blockIdx.x;
        bz = l >> 8; bx = l & 3; by = (l >> 2) & 63;
    }
    const f16* Ab = A + (long)bz * sA;
    const f16* Bb = B + (long)bz * sB;
    const int bm0 = by * 256;
    const int bn0 = bx * 256;

    const int tid  = threadIdx.x;
    const int lane = tid & 63;
    const int wid  = tid >> 6;
    const int wm   = (wid >> 2) * 128;   // 2 wave-rows x 128
    const int wn   = (wid & 3)  * 64;    // 4 wave-cols x 64
    const int lr   = lane & 15;
    const int quad = lane >> 4;
    const int kb   = (quad ^ ((lr >> 1) & 3)) << 3;  // swizzled k-block read offset

    const int offA = (wm + lr) * 32 + kb;   // + rg*512
    const int offB = (wn + lr) * 32 + kb;   // + cg*512

    // Staging source pointers: slot n = sweep*512 + tid; r = n>>2, c = n&3;
    // slot holds global k-block c ^ ((r>>1)&3). Sweep 1 = rows +128, same swizzle.
    const int r0 = tid >> 2, c0 = tid & 3;
    const int sw = (c0 ^ ((r0 >> 1) & 3)) << 3;
    const f16* gAs = Ab + (long)(bm0 + r0) * K + sw;
    const f16* gBs = Bb + (long)(bn0 + r0) * K + sw;
    const long sweep = (long)128 * K;

    f16* ldsAw = smem + wid * 512;           // + buf*16384, sweep1 at +4096
    f16* ldsBw = smem + 8192 + wid * 512;

    f32x4 acc[8][4] = {};
    f32x4 rs[8] = {};          // EPI==2: rowsum accumulators (ones-MFMA)
    f16x8 bones;
#pragma unroll
    for (int j = 0; j < 8; ++j) bones[j] = (f16)1.0f;

    const int nt = K >> 5;     // K-tiles of 32; EPI==1 requires nt == 32

    // Mask prefetch state (EPI==1 only; DCE'd otherwise). Two static buffers.
    int mv0[8], mv1[8];
    unsigned mw[4] = {0u, 0u, 0u, 0u};
    const int* Mrow = Mask + (long)bz * sMask
                    + (long)(bm0 + wm + quad * 4) * N + (bn0 + wn + lr);

    // Prologue: stage tiles 0,1,2 (12 gl_lds); vmcnt(8) -> tile 0 landed.
#pragma unroll
    for (int tt = 0; tt < 3; ++tt) {
        const f16* gA = gAs + (long)tt * 32;
        const f16* gB = gBs + (long)tt * 32;
        f16* dA = ldsAw + tt * 16384;
        f16* dB = ldsBw + tt * 16384;
        gl_lds16(gA, dA);
        gl_lds16(gA + sweep, dA + 4096);
        gl_lds16(gB, dB);
        gl_lds16(gB + sweep, dB + 4096);
    }
    asm volatile("s_waitcnt vmcnt(8)" ::: "memory");
    BAR();

    if constexpr (EPI == 1) {
        // nt == 32. Window = tiles 16..31, 8 mask dwords/tile.
        // Queue audit (groups: stg=4, mask=8; vmcnt retires in issue order):
        //   t<16, vmcnt(4): survivors [stg t+3]; stg t+2 forced end of t.
        //   t=16: q=[stg18]+[stg19,m0]=16 -> vm12 forces stg18.
        //   t=17: q=[stg19,m0]+[stg20,m1]=24 -> vm12 forces stg19,m0.
        //   steady t: q=[stg t+2,m(t-17)]+[stg t+3,m(t-16)]=24 -> vm12 forces
        //     stg t+2 (read t+2: 1-barrier slack) and m(t-17) (packed t+1 ok;
        //     we pack at t+2). Budget m: issue mid-t .. end t+1 ~ 1.5 tiles.
        //   t=28 (last staged): steady form.
        //   t=29: q=[stg31,m12]+[m13]=20 -> vm8 forces stg31,m12.
        //   t=30: q=[m13]+[m14]=16 -> vm8 forces m13.
        //   t=31: q=[m14]+[m15]=16 -> vm0 forces all; pack m14,m15 after.
#pragma unroll 1
        for (int t = 0; t < 16; ++t) {
            STAGE_T(t);
            COMPUTE_T(t, "s_waitcnt vmcnt(4)");
        }
        { STAGE_T(16); MASK_ISSUE_P(0, mv0); COMPUTE_T(16, VM12); }
        { STAGE_T(17); MASK_ISSUE_P(1, mv1); COMPUTE_T(17, VM12); }
#pragma unroll 1
        for (int tt = 18; tt < 28; tt += 2) {
            { MASK_PACK_P(tt - 18, mv0); STAGE_T(tt);
              MASK_ISSUE_P(tt - 16, mv0); COMPUTE_T(tt, VM12); }
            { MASK_PACK_P(tt - 17, mv1); STAGE_T(tt + 1);
              MASK_ISSUE_P(tt - 15, mv1); COMPUTE_T(tt + 1, VM12); }
        }
        { MASK_PACK_P(10, mv0); STAGE_T(28); MASK_ISSUE_P(12, mv0);
          COMPUTE_T(28, VM12); }
        { MASK_PACK_P(11, mv1); MASK_ISSUE_P(13, mv1); COMPUTE_T(29, VM8); }
        { MASK_PACK_P(12, mv0); MASK_ISSUE_P(14, mv0); COMPUTE_T(30, VM8); }
        { MASK_PACK_P(13, mv1); MASK_ISSUE_P(15, mv1);
          COMPUTE_T(31, "s_waitcnt vmcnt(0)"); }
        MASK_PACK_P(14, mv0);
        MASK_PACK_P(15, mv1);
    } else {
        // Main loop: vmcnt(4) at end of tile t leaves only t+3's staging in
        // flight -> t+2 resident one full tile before its reads.
#pragma unroll 1
        for (int t = 0; t < nt - 3; ++t) {
            STAGE_T(t);
            COMPUTE_T(t, "s_waitcnt vmcnt(4)");
        }
        COMPUTE_T(nt - 3, "s_waitcnt vmcnt(4)");
        COMPUTE_T(nt - 2, "s_waitcnt vmcnt(0)");
        COMPUTE_T(nt - 1, "");
    }

    // Epilogue. C/D layout: col = lane&15, row = quad*4 + reg.
    if constexpr (EPI == 0) {
        f16* C = (f16*)Cv + (long)bz * sC;
#pragma unroll
        for (int rg = 0; rg < 8; ++rg)
#pragma unroll
            for (int cg = 0; cg < 4; ++cg)
#pragma unroll
                for (int r = 0; r < 4; ++r) {
                    long idx = (long)(bm0 + wm + rg * 16 + quad * 4 + r) * N
                             + (bn0 + wn + cg * 16 + lr);
                    C[idx] = (f16)acc[rg][cg][r];
                }
    } else if constexpr (EPI == 1) {
        f16* C = (f16*)Cv + (long)bz * sC;
#pragma unroll
        for (int rg = 0; rg < 8; ++rg)
#pragma unroll
            for (int cg = 0; cg < 4; ++cg)
#pragma unroll
                for (int r = 0; r < 4; ++r) {
                    const int linear = rg * 16 + cg * 4 + r;
                    bool keep = (mw[linear >> 5] >> (linear & 31)) & 1u;
                    long idx = (long)(bm0 + wm + rg * 16 + quad * 4 + r) * N
                             + (bn0 + wn + cg * 16 + lr);
                    float e = __expf(acc[rg][cg][r] * 0.03125f);
                    C[idx] = keep ? (f16)e : (f16)0.0f;  // == exp(-1e10/32)
                }
    } else {
        float* C = (float*)Cv + (long)bz * sC;
#pragma unroll
        for (int rg = 0; rg < 8; ++rg) {
            float inv[4];
#pragma unroll
            for (int r = 0; r < 4; ++r) {
                float s = rs[rg][r];                 // rowsum of row quad*4+r —
                inv[r] = (s > 0.f) ? 1.0f / s : 0.f; // same C/D slot
            }
#pragma unroll
            for (int cg = 0; cg < 4; ++cg)
#pragma unroll
                for (int r = 0; r < 4; ++r) {
                    long idx = (long)(bm0 + wm + rg * 16 + quad * 4 + r) * N
                             + (bn0 + wn + cg * 16 + lr);
                    C[idx] = acc[rg][cg][r] * inv[r];
                }
        }
    }
}

// fp32 -> f16 for all five inputs in ONE dispatch. Grid 35840 blocks:
//   [0,16384) h1, [16384,32768) h2, then 1024 each for Wq, Wk, Wv.
__global__ __launch_bounds__(256)
void cvt_all(const float* __restrict__ h1, const float* __restrict__ h2,
             const float* __restrict__ wq, const float* __restrict__ wk,
             const float* __restrict__ wv,
             f16* __restrict__ oh1, f16* __restrict__ oh2,
             f16* __restrict__ owq, f16* __restrict__ owk,
             f16* __restrict__ owv)
{
    int bid = blockIdx.x;
    const float* s; f16* d;
    if (bid < 16384)      { s = h1; d = oh1; }
    else if (bid < 32768) { s = h2; d = oh2; bid -= 16384; }
    else if (bid < 33792) { s = wq; d = owq; bid -= 32768; }
    else if (bid < 34816) { s = wk; d = owk; bid -= 33792; }
    else                  { s = wv; d = owv; bid -= 34816; }
    long i = ((long)bid * 256 + threadIdx.x) * 4;
    float4 v = *(const float4*)(s + i);
    f16x4 o;
    o[0] = (f16)v.x; o[1] = (f16)v.y; o[2] = (f16)v.z; o[3] = (f16)v.w;
    *(f16x4*)(d + i) = o;
}

extern "C" void kernel_launch(void* const* d_in, const int* in_sizes, int n_in,
                              void* d_out, int out_size, void* d_ws, size_t ws_size,
                              hipStream_t stream)
{
    const float* h1   = (const float*)d_in[0];
    const float* h2   = (const float*)d_in[1];
    const int*   mask = (const int*)d_in[2];
    const float* Wq   = (const float*)d_in[3];
    const float* Wk   = (const float*)d_in[4];
    const float* Wv   = (const float*)d_in[5];
    float* out = (float*)d_out;

    char* ws = (char*)d_ws;
    f16* h1f = (f16*)(ws);
    f16* h2f = (f16*)(ws + 33554432);
    f16* Wqf = (f16*)(ws + 67108864);
    f16* Wkf = (f16*)(ws + 69206016);
    f16* Wvf = (f16*)(ws + 71303168);
    f16* SP  = (f16*)(ws + 33554432);           // over dead h2f+Wf
    f16* Vt  = (f16*)(ws);                      // over dead h1f
    f16* Qf  = (f16*)d_out;
    f16* Kp  = (f16*)((char*)d_out + 33554432);

    dim3 blk(256);
    dim3 blk5(512);

    cvt_all<<<dim3(35840), blk, 0, stream>>>(h1, h2, Wq, Wk, Wv,
                                             h1f, h2f, Wqf, Wkf, Wvf);

    // Q = h1 @ Wq^T and K = h2 @ Wk^T fused: 512 blocks, kind = l>>8.
    // sA/sB/sC are the element offsets h1f->h2f, Wqf->Wkf, Qf->Kp.
    gemm256_nt_f16<0, 2, 0><<<dim3(512), blk5, 0, stream>>>(h1f, Wqf, Qf,
        nullptr, 1024, 1024, 16777216, 1048576, 16777216, 0);
    // Vt[b] = Wv @ h2[b]^T  (1024x2048, K=1024) -> over dead h1f
    gemm256_nt_f16<0, 0, 0><<<dim3(8, 4, 8), blk5, 0, stream>>>(Wvf, h2f, Vt,
        nullptr, 2048, 1024, 0, (long)2048 * 1024, (long)1024 * 2048, 0);
    // P' = exp(mask_scale(Q @ K^T))  (2048x2048, K=1024), 1D xcd grid (LGX=3)
    gemm256_nt_f16<1, 1, 3><<<dim3(512), blk5, 0, stream>>>(Qf, Kp, SP,
        mask, 2048, 1024, (long)2048 * 1024, (long)2048 * 1024,
        (long)2048 * 2048, (long)2048 * 2048);
    // out[b] = (P'[b] @ Vt[b]^T) / rowsum  (2048x1024, K=2048), 1D xcd (LGX=2)
    gemm256_nt_f16<2, 1, 2><<<dim3(256), blk5, 0, stream>>>(SP, Vt, out,
        nullptr, 1024, 2048, (long)2048 * 2048, (long)1024 * 2048,
        (long)2048 * 1024, 0);
}